// Round 8
// baseline (140.041 us; speedup 1.0000x reference)
//
#include <hip/hip_runtime.h>

#define BATCH 16384
#define LAYERS 63
#define BM 128
#define XS 72              // Hs row stride in bf16: 144 B (36 words -> 2-way alias = free)
#define BLOB_BYTES 21504   // W1 8192 | W2 8192 | b1 256 | b2 256 | W3 4096 | b3 128 | pad
#define LDS_IMG 8192       // LDS image = W2 only -> 26624 B total w/ Hs -> 6 blocks/CU

typedef float f4 __attribute__((ext_vector_type(4)));
typedef short s8 __attribute__((ext_vector_type(8)));          // 8 x bf16
typedef unsigned int u4 __attribute__((ext_vector_type(4)));   // same 16 B as s8

#define LOG2E  1.442695041f
#define LN2    0.6931471806f
#define SCALE2 2.885390082f   // 2*log2e: W1,b1,W2,b2 pre-scale (tanh mul folded)

__device__ __forceinline__ float rcpf(float v) { return __builtin_amdgcn_rcpf(v); }

__device__ __forceinline__ float exp2_hw(float x) {   // single v_exp_f32
#if __has_builtin(__builtin_amdgcn_exp2f)
    return __builtin_amdgcn_exp2f(x);
#else
    return exp2f(x);
#endif
}

// tanh for PRE-SCALED input (acc = 2*log2e * true_preact):
//   tanh(t) = 1 - 2/(exp2(acc)+1) — 4 instructions. Measured-minimal (r6).
__device__ __forceinline__ float fast_tanh_pre(float v) {
    float e = exp2_hw(v);
    return 1.f - 2.f * rcpf(e + 1.f);
}
// derivs chain on RAW param: 1e-3 + softplus(softplus(p)) == 1e-3 + ln(2+e^p)
__device__ __forceinline__ float deriv_chain_raw(float p) {
    return 1e-3f + LN2 * __log2f(2.f + exp2_hw(p * LOG2E));
}
// same, param pre-scaled by log2e (hot path; W3/b3 blob images carry the scale)
__device__ __forceinline__ float deriv_chain_pre(float pp) {
    return 1e-3f + LN2 * __log2f(2.f + exp2_hw(pp));
}
__device__ __forceinline__ unsigned short f2bf(float f) {   // RNE fp32->bf16
    unsigned int u = __float_as_uint(f);
    u += 0x7fffu + ((u >> 16) & 1u);
    return (unsigned short)(u >> 16);
}
#if __has_builtin(__builtin_amdgcn_cvt_pk_bf16_f32)
__device__ __forceinline__ unsigned pk2(float a, float b) {   // gfx950 packed cvt
    auto r = __builtin_amdgcn_cvt_pk_bf16_f32(a, b);
    return __builtin_bit_cast(unsigned, r);
}
#else
__device__ __forceinline__ unsigned pk2(float a, float b) {
    return (unsigned)f2bf(a) | ((unsigned)f2bf(b) << 16);
}
#endif
__device__ __forceinline__ unsigned long long pack4(float a, float b, float c, float d) {
    return (unsigned long long)pk2(a, b) | ((unsigned long long)pk2(c, d) << 32);
}

// Register-array RQS on RAW params (prep's d=0 path only; hot path inlined).
__device__ __forceinline__ void rqs_eval(const float* p, float xv, float& zout, float& ldout) {
    const bool inside = (xv >= -3.f) && (xv <= 3.f);
    const float xi = fminf(fmaxf(xv, -3.f), 3.f);

    float wa[8], ha[8];
    {   // widths = affine(softmax(6*softmax(p[0:8]))) — no max-sub (range-safe)
        float s = 0.f;
        #pragma unroll
        for (int i = 0; i < 8; i++) { wa[i] = exp2_hw(p[i] * LOG2E); s += wa[i]; }
        float inv = 6.f * rcpf(s);
        #pragma unroll
        for (int i = 0; i < 8; i++) wa[i] *= inv;
        s = 0.f;
        #pragma unroll
        for (int i = 0; i < 8; i++) { wa[i] = exp2_hw(wa[i] * LOG2E); s += wa[i]; }
        inv = 0.992f * rcpf(s);
        #pragma unroll
        for (int i = 0; i < 8; i++) wa[i] = 1e-3f + wa[i] * inv;
    }
    {
        float s = 0.f;
        #pragma unroll
        for (int i = 0; i < 8; i++) { ha[i] = exp2_hw(p[8 + i] * LOG2E); s += ha[i]; }
        float inv = 6.f * rcpf(s);
        #pragma unroll
        for (int i = 0; i < 8; i++) ha[i] *= inv;
        s = 0.f;
        #pragma unroll
        for (int i = 0; i < 8; i++) { ha[i] = exp2_hw(ha[i] * LOG2E); s += ha[i]; }
        inv = 0.992f * rcpf(s);
        #pragma unroll
        for (int i = 0; i < 8; i++) ha[i] = 1e-3f + ha[i] * inv;
    }

    float cw[9], ch[9];
    cw[0] = -3.f; ch[0] = -3.f;
    {
        float cs = 0.f, hs = 0.f;
        #pragma unroll
        for (int k = 1; k < 8; k++) {
            cs += wa[k - 1]; cw[k] = 6.f * cs - 3.f;
            hs += ha[k - 1]; ch[k] = 6.f * hs - 3.f;
        }
    }
    cw[8] = 3.f; ch[8] = 3.f;

    int cnt = 0;
    #pragma unroll
    for (int k = 0; k < 8; k++) cnt += (xi >= cw[k]) ? 1 : 0;
    cnt += (xi >= 3.000001f) ? 1 : 0;
    const int bin = min(max(cnt - 1, 0), 7);

    float in_cw = 0.f, in_w = 1.f, in_ch = 0.f, in_h = 1.f;
    float pd0 = 0.f, pd1 = 0.f;
    #pragma unroll
    for (int k = 0; k < 8; k++)
        if (k == bin) {
            in_cw = cw[k]; in_w = cw[k + 1] - cw[k];
            in_ch = ch[k]; in_h = ch[k + 1] - ch[k];
            if (k >= 1) pd0 = p[15 + k];
            if (k <= 6) pd1 = p[16 + k];
        }
    // boundary derivs are exactly 1.0
    const float dk  = (bin == 0) ? 1.f : deriv_chain_raw(pd0);
    const float dk1 = (bin == 7) ? 1.f : deriv_chain_raw(pd1);

    const float rw    = rcpf(in_w);
    const float delta = in_h * rw;
    const float th    = (xi - in_cw) * rw;
    const float omt = 1.f - th;
    const float t1  = th * omt;
    const float th2 = th * th;
    const float numer = in_h * (delta * th2 + dk * t1);
    const float denom = delta + (dk + dk1 - 2.f * delta) * t1;
    const float rd    = rcpf(denom);
    const float outv  = in_ch + numer * rd;
    const float dnum  = delta * delta * (dk1 * th2 + 2.f * delta * t1 + dk * omt * omt);
    const float ldv = LN2 * __log2f(dnum * rd * rd);

    zout  = inside ? outv : xv;
    ldout = inside ? ldv : 0.f;
}

// Prep: x -> bf16; weights -> per-layer swizzled bf16 blob with CONSTANT
// PRE-SCALES folded in: W1,b1,W2,b2 x= 2*log2e, W3,b3 x= log2e. Layout:
//   W1 @0 | W2 @8192 | b1 @16384 | b2 @16640 | W3 @16896 | b3 @20992 | pad
__global__ __launch_bounds__(256) void prep_kernel(
    const float* __restrict__ x, const float* __restrict__ init_param,
    const float* __restrict__ W1, const float* __restrict__ W2, const float* __restrict__ W3,
    const float* __restrict__ b1, const float* __restrict__ b2, const float* __restrict__ b3,
    unsigned short* __restrict__ x_bf, unsigned char* __restrict__ blobG,
    float* __restrict__ z, float* __restrict__ ld)
{
    const int tid = threadIdx.x;
    if (blockIdx.x < 1024) {                    // x convert: 262144 quads
        size_t idx = (size_t)blockIdx.x * 256 + tid;
        f4 v = *(const f4*)&x[idx * 4];
        *(unsigned long long*)&x_bf[idx * 4] = pack4(v[0], v[1], v[2], v[3]);
        return;
    }
    if (blockIdx.x >= 1024 + LAYERS) {          // d = 0 spline + ld seed
        const int row = (blockIdx.x - 1024 - LAYERS) * 256 + tid;
        float p[23];
        #pragma unroll
        for (int j = 0; j < 23; j++) p[j] = init_param[j];
        float zv, lv;
        rqs_eval(p, x[(size_t)row * 64], zv, lv);
        z[(size_t)row * 64] = zv;
        ld[row] = lv;
        return;
    }
    const int l = blockIdx.x - 1024;
    unsigned char* gb = blobG + (size_t)l * BLOB_BYTES;
    for (int e = tid; e < 1024; e += 256) {     // W1|W2: (m, row r, block j), XOR-8 swizzle
        int m = e >> 9, r = (e >> 3) & 63, j = e & 7;
        const float* src = (m ? W2 : W1) + (size_t)l * 4096 + r * 64 + j * 8;
        unsigned long long lo = pack4(src[0] * SCALE2, src[1] * SCALE2, src[2] * SCALE2, src[3] * SCALE2);
        unsigned long long hi = pack4(src[4] * SCALE2, src[5] * SCALE2, src[6] * SCALE2, src[7] * SCALE2);
        unsigned long long* dst = (unsigned long long*)(gb + m * 8192 + r * 128 + ((j ^ (r & 7)) << 4));
        dst[0] = lo; dst[1] = hi;
    }
    if (tid < 256) {                            // W3 @16896, padded to 32 rows, x log2e
        int r = tid >> 3, j = tid & 7;
        unsigned long long lo = 0ull, hi = 0ull;
        if (r < 23) {
            const float* src = W3 + (size_t)l * 1472 + r * 64 + j * 8;
            lo = pack4(src[0] * LOG2E, src[1] * LOG2E, src[2] * LOG2E, src[3] * LOG2E);
            hi = pack4(src[4] * LOG2E, src[5] * LOG2E, src[6] * LOG2E, src[7] * LOG2E);
        }
        unsigned long long* dst = (unsigned long long*)(gb + 16896 + r * 128 + ((j ^ (r & 7)) << 4));
        dst[0] = lo; dst[1] = hi;
    }
    if (tid < 64)        *(float*)(gb + 16384 + tid * 4)         = b1[l * 64 + tid] * SCALE2;
    else if (tid < 128)  *(float*)(gb + 16640 + (tid - 64) * 4)  = b2[l * 64 + tid - 64] * SCALE2;
    else if (tid < 160)  *(float*)(gb + 20992 + (tid - 128) * 4) = (tid - 128 < 23) ? b3[l * 23 + tid - 128] * LOG2E : 0.f;
    else                 { int e = tid - 160; if (e < 96) *(float*)(gb + 21120 + e * 4) = 0.f; }
}

// One block = one layer x one 128-row tile (8064 blocks). LDS = W2 only (8 KB
// DMA) + Hs (18 KB) = 26624 B -> 6 blocks/CU. ALL biases + W1/W3 frags come
// straight from the L2-hot global blob (same address across a layer's 128
// blocks -> L2 broadcast). KEY r8 change: the DMA-drain barrier moved from
// before GEMM1 to after it — GEMM1 touches no LDS (b1 from global, Hs writes
// are wave-own), so its 16 MFMA + 32-tanh epilogue now hide the W2 DMA
// latency instead of stalling on it. Cross-wave deps preserved: barrier1 =
// W2 DMA -> GEMM2 reads; barrier2 = Ps writes -> RQS reads. Lessons ledger:
// r2 W2-in-VGPR = regalloc chaos; r4 f2 ext-vector = marshal movs; r5 poly =
// more instrs; r6 4-instr tanh = issue floor; r7 LDS diet -> 6 blk/CU.
__global__ __launch_bounds__(256, 6) void mlp_rqs_kernel(
    const float* __restrict__ x, const unsigned short* __restrict__ x_bf,
    const unsigned char* __restrict__ blobG,
    float* __restrict__ z, float* __restrict__ ld)
{
    const int l = blockIdx.y, keff = l + 1;
    const int b0 = blockIdx.x * BM;
    const int tid = threadIdx.x;
    const int ln = tid & 63, wv = tid >> 6;
    const int c = ln & 15, q = ln >> 4;
    const int mbase = wv * 32;
    const int c7 = c & 7;

    __shared__ __align__(16) unsigned char blob[LDS_IMG];
    __shared__ __align__(16) unsigned short Hs[BM * XS];

    unsigned short* W2s = (unsigned short*)blob;            // rows 0..63, swizzled
    float* PsF = (float*)Hs;   // Ps row r: 24 floats at word r*36 (overlay, h2 dead)

    const unsigned char* gblob = blobG + (size_t)l * BLOB_BYTES;
    const float* b1g = (const float*)(gblob + 16384);
    const float* b2g = (const float*)(gblob + 16640);

    // ---- async DMA: W2 (8 KB, 8 clean full-wave 1KB chunks), once per block.
    //      NOT waited here — GEMM1 runs under it; barrier after GEMM1 drains.
    for (int t = wv; t < 8; t += 4)
        __builtin_amdgcn_global_load_lds(
            (const __attribute__((address_space(1))) void*)(gblob + 8192 + t * 1024 + ln * 16),
            (__attribute__((address_space(3))) void*)(blob + t * 1024 + ln * 16), 16, 0, 0);

    const int ks1 = (keff + 31) >> 5;     // 1 or 2

    // ---- W1 A-frags -> VGPR (swizzled image, L2-hot) ----
    s8 aw1[2][4];
    #pragma unroll
    for (int mt = 0; mt < 4; mt++)
        aw1[0][mt] = *(const s8*)(gblob + (mt * 16 + c) * 128 + ((q ^ c7) << 4));
    if (ks1 == 2) {
        #pragma unroll
        for (int mt = 0; mt < 4; mt++)
            aw1[1][mt] = *(const s8*)(gblob + (mt * 16 + c) * 128 + (((4 + q) ^ c7) << 4));
    }

    // ---- X B-frags (batch rows mbase+c, mbase+16+c), tril mask in-register ----
    u4 B0u, B1u, B2u{}, B3u{};
    {
        const unsigned short* xr = x_bf + (size_t)(b0 + mbase + c) * 64 + q * 8;
        B0u = *(const u4*)xr;  B1u = *(const u4*)(xr + 1024);
        if (ks1 == 2) { B2u = *(const u4*)(xr + 32); B3u = *(const u4*)(xr + 1024 + 32); }
        const int n = keff - ((ks1 - 1) * 32 + q * 8);   // valid elems in boundary chunk
        unsigned mk[4];
        #pragma unroll
        for (int i = 0; i < 4; i++) {
            int m = n - 2 * i;
            mk[i] = (m >= 2) ? 0xFFFFFFFFu : ((m == 1) ? 0xFFFFu : 0u);
        }
        if (ks1 == 2) {
            #pragma unroll
            for (int i = 0; i < 4; i++) { B2u[i] &= mk[i]; B3u[i] &= mk[i]; }
        } else {
            #pragma unroll
            for (int i = 0; i < 4; i++) { B0u[i] &= mk[i]; B1u[i] &= mk[i]; }
        }
    }
    const float xv = x[(size_t)(b0 + (tid & 127)) * 64 + keff];   // RQS input (f32 exact)

    // ---- GEMM1: H1 = tanh(W1 X^T + b1), K truncated by tril. No LDS reads;
    //      runs entirely under the W2 DMA. b1 from global (L2 broadcast). ----
    {
        f4 acc[4][2];
        #pragma unroll
        for (int mt = 0; mt < 4; mt++) {
            f4 bv = *(const f4*)&b1g[mt * 16 + q * 4];
            acc[mt][0] = bv; acc[mt][1] = bv;
        }
        {
            s8 bx0 = __builtin_bit_cast(s8, B0u), bx1 = __builtin_bit_cast(s8, B1u);
            #pragma unroll
            for (int mt = 0; mt < 4; mt++) {
                acc[mt][0] = __builtin_amdgcn_mfma_f32_16x16x32_bf16(aw1[0][mt], bx0, acc[mt][0], 0, 0, 0);
                acc[mt][1] = __builtin_amdgcn_mfma_f32_16x16x32_bf16(aw1[0][mt], bx1, acc[mt][1], 0, 0, 0);
            }
        }
        if (ks1 == 2) {
            s8 bx0 = __builtin_bit_cast(s8, B2u), bx1 = __builtin_bit_cast(s8, B3u);
            #pragma unroll
            for (int mt = 0; mt < 4; mt++) {
                acc[mt][0] = __builtin_amdgcn_mfma_f32_16x16x32_bf16(aw1[1][mt], bx0, acc[mt][0], 0, 0, 0);
                acc[mt][1] = __builtin_amdgcn_mfma_f32_16x16x32_bf16(aw1[1][mt], bx1, acc[mt][1], 0, 0, 0);
            }
        }
        #pragma unroll
        for (int mt = 0; mt < 4; mt++)
            #pragma unroll
            for (int nt = 0; nt < 2; nt++) {
                f4 a = acc[mt][nt];
                unsigned long long w = (unsigned long long)pk2(fast_tanh_pre(a[0]), fast_tanh_pre(a[1]))
                    | ((unsigned long long)pk2(fast_tanh_pre(a[2]), fast_tanh_pre(a[3])) << 32);
                *(unsigned long long*)&Hs[(mbase + nt * 16 + c) * XS + mt * 16 + q * 4] = w;
            }
    }

    __syncthreads();   // W2 DMA resident (only cross-wave dep up to GEMM2)

    // ---- GEMM2: H2 = tanh(W2 H1^T + b2), wave-own rows, no barrier ----
    {
        f4 acc[4][2];
        #pragma unroll
        for (int mt = 0; mt < 4; mt++) {
            f4 bv = *(const f4*)&b2g[mt * 16 + q * 4];
            acc[mt][0] = bv; acc[mt][1] = bv;
        }
        #pragma unroll
        for (int ks = 0; ks < 2; ks++) {
            s8 bh0 = *(const s8*)&Hs[(mbase + c) * XS + ks * 32 + q * 8];
            s8 bh1 = *(const s8*)&Hs[(mbase + 16 + c) * XS + ks * 32 + q * 8];
            const int sb = ((ks * 4 + q) ^ c7) * 8;
            #pragma unroll
            for (int mt = 0; mt < 4; mt++) {
                s8 aw = *(const s8*)&W2s[(mt * 16 + c) * 64 + sb];
                acc[mt][0] = __builtin_amdgcn_mfma_f32_16x16x32_bf16(aw, bh0, acc[mt][0], 0, 0, 0);
                acc[mt][1] = __builtin_amdgcn_mfma_f32_16x16x32_bf16(aw, bh1, acc[mt][1], 0, 0, 0);
            }
        }
        #pragma unroll
        for (int mt = 0; mt < 4; mt++)
            #pragma unroll
            for (int nt = 0; nt < 2; nt++) {
                f4 a = acc[mt][nt];
                unsigned long long w = (unsigned long long)pk2(fast_tanh_pre(a[0]), fast_tanh_pre(a[1]))
                    | ((unsigned long long)pk2(fast_tanh_pre(a[2]), fast_tanh_pre(a[3])) << 32);
                *(unsigned long long*)&Hs[(mbase + nt * 16 + c) * XS + mt * 16 + q * 4] = w;
            }
    }

    // ---- GEMM3: OUT = W3 H2^T + b3 (23 outs padded 32, along m) ----
    // W3 frags (16 VGPR) + b3 straight from L2-hot blob — aw1 dead by now.
    {
        f4 acc3[2][2];
        #pragma unroll
        for (int mt = 0; mt < 2; mt++) {
            f4 bv = *(const f4*)(gblob + 20992 + (mt * 16 + q * 4) * 4);
            acc3[mt][0] = bv; acc3[mt][1] = bv;
        }
        s8 aw3[2][2];
        #pragma unroll
        for (int ks = 0; ks < 2; ks++)
            #pragma unroll
            for (int mt = 0; mt < 2; mt++)
                aw3[ks][mt] = *(const s8*)(gblob + 16896 + (mt * 16 + c) * 128 + (((ks * 4 + q) ^ c7) << 4));
        #pragma unroll
        for (int ks = 0; ks < 2; ks++) {
            s8 bh0 = *(const s8*)&Hs[(mbase + c) * XS + ks * 32 + q * 8];
            s8 bh1 = *(const s8*)&Hs[(mbase + 16 + c) * XS + ks * 32 + q * 8];
            #pragma unroll
            for (int mt = 0; mt < 2; mt++) {
                acc3[mt][0] = __builtin_amdgcn_mfma_f32_16x16x32_bf16(aw3[ks][mt], bh0, acc3[mt][0], 0, 0, 0);
                acc3[mt][1] = __builtin_amdgcn_mfma_f32_16x16x32_bf16(aw3[ks][mt], bh1, acc3[mt][1], 0, 0, 0);
            }
        }
        // Ps overlay on wave-own Hs rows (h2 dead): b128 writes
        #pragma unroll
        for (int mt = 0; mt < 2; mt++)
            #pragma unroll
            for (int nt = 0; nt < 2; nt++)
                *(f4*)&PsF[(mbase + nt * 16 + c) * 36 + mt * 16 + q * 4] = acc3[mt][nt];
    }
    __syncthreads();   // Ps complete across waves

    // ---- fused RQS: one thread per row (params pre-scaled by log2e) ----
    if (tid < BM) {
        const float* prow = &PsF[tid * 36];
        f4 pv0 = *(const f4*)(prow + 0);
        f4 pv1 = *(const f4*)(prow + 4);
        f4 pv2 = *(const f4*)(prow + 8);
        f4 pv3 = *(const f4*)(prow + 12);

        const bool inside = (xv >= -3.f) && (xv <= 3.f);
        const float xi = fminf(fmaxf(xv, -3.f), 3.f);

        float e[8];
        // ---- widths: double softmax, 6-scaled ----
        float s = 0.f;
        #pragma unroll
        for (int i = 0; i < 4; i++) { e[i]     = exp2_hw(pv0[i]); s += e[i]; }
        #pragma unroll
        for (int i = 0; i < 4; i++) { e[4 + i] = exp2_hw(pv1[i]); s += e[4 + i]; }
        float inv2 = (6.f * LOG2E) * rcpf(s);            // exp(6*e/s) = exp2(e*inv2)
        float s2 = 0.f;
        #pragma unroll
        for (int i = 0; i < 8; i++) { e[i] = exp2_hw(e[i] * inv2); s2 += e[i]; }
        float inv3 = (6.f * 0.992f) * rcpf(s2);          // width_k = 6e-3 + e*inv3 (sum=6)

        float w6k  = 6e-3f + e[0] * inv3;                 // w6[0]
        float cs   = -3.f + w6k;                          // cw[1]
        float in_cw = -3.f, in_w = w6k;
        int bin = 0;
        #pragma unroll
        for (int k = 1; k < 8; k++) {
            w6k = 6e-3f + e[k] * inv3;
            const bool ge = (xi >= cs);                   // xi >= cw[k]
            in_cw = ge ? cs  : in_cw;
            in_w  = ge ? w6k : in_w;
            bin   = ge ? k   : bin;
            cs += w6k;                                    // -> cw[k+1]
        }

        // ---- heights: same chain, select by bin ----
        s = 0.f;
        #pragma unroll
        for (int i = 0; i < 4; i++) { e[i]     = exp2_hw(pv2[i]); s += e[i]; }
        #pragma unroll
        for (int i = 0; i < 4; i++) { e[4 + i] = exp2_hw(pv3[i]); s += e[4 + i]; }
        inv2 = (6.f * LOG2E) * rcpf(s);
        s2 = 0.f;
        #pragma unroll
        for (int i = 0; i < 8; i++) { e[i] = exp2_hw(e[i] * inv2); s2 += e[i]; }
        inv3 = (6.f * 0.992f) * rcpf(s2);

        float h6p = 6e-3f + e[0] * inv3;                  // h6[0]
        float csh = -3.f, in_ch = -3.f, in_h = h6p;
        #pragma unroll
        for (int k = 1; k < 8; k++) {
            csh += h6p;                                   // ch[k]
            h6p = 6e-3f + e[k] * inv3;                    // h6[k]
            const bool sel = (bin >= k);
            in_ch = sel ? csh : in_ch;
            in_h  = sel ? h6p : in_h;
        }

        // ---- derivatives: indexed LDS reads (in-row garbage at edges, masked) ----
        const float pd0 = prow[15 + bin];
        const float pd1 = prow[16 + bin];
        const float dk  = (bin == 0) ? 1.f : deriv_chain_pre(pd0);
        const float dk1 = (bin == 7) ? 1.f : deriv_chain_pre(pd1);

        const float rw    = rcpf(in_w);
        const float delta = in_h * rw;
        const float th    = (xi - in_cw) * rw;
        const float omt = 1.f - th;
        const float t1  = th * omt;
        const float th2 = th * th;
        const float numer = in_h * (delta * th2 + dk * t1);
        const float denom = delta + (dk + dk1 - 2.f * delta) * t1;
        const float rd    = rcpf(denom);
        const float outv  = in_ch + numer * rd;
        const float dnum  = delta * delta * (dk1 * th2 + 2.f * delta * t1 + dk * omt * omt);
        const float ldv = LN2 * __log2f(dnum * rd * rd);

        z[(size_t)(b0 + tid) * 64 + keff] = inside ? outv : xv;
        unsafeAtomicAdd(ld + b0 + tid, inside ? ldv : 0.f);
    }
}

extern "C" void kernel_launch(void* const* d_in, const int* in_sizes, int n_in,
                              void* d_out, int out_size, void* d_ws, size_t ws_size,
                              hipStream_t stream)
{
    const float* x  = (const float*)d_in[0];
    const float* ip = (const float*)d_in[1];
    const float* W1 = (const float*)d_in[2];
    const float* b1 = (const float*)d_in[3];
    const float* W2 = (const float*)d_in[4];
    const float* b2 = (const float*)d_in[5];
    const float* W3 = (const float*)d_in[6];
    const float* b3 = (const float*)d_in[7];

    float* z  = (float*)d_out;                  // [B][64]
    float* ld = z + (size_t)BATCH * 64;         // [B]

    unsigned short* x_bf = (unsigned short*)d_ws;                         // [B][64] bf16
    unsigned char*  blobG = (unsigned char*)(x_bf + (size_t)BATCH * 64);  // 63 * 21504 B

    // grid: 1024 x-convert | 63 blob | 64 d0-spline blocks
    prep_kernel<<<1024 + LAYERS + 64, 256, 0, stream>>>(
        x, ip, W1, W2, W3, b1, b2, b3, x_bf, blobG, z, ld);
    mlp_rqs_kernel<<<dim3(BATCH / BM, LAYERS), 256, 0, stream>>>(
        x, x_bf, blobG, z, ld);
}

// Round 9
// 125.467 us; speedup vs baseline: 1.1162x; 1.1162x over previous
//
#include <hip/hip_runtime.h>

#define BATCH 16384
#define LAYERS 63
#define BM 128
#define XS 72              // Hs row stride in bf16: 144 B (stride 36 words -> 2-way
                           // bank alias only = free; 64/80 would be 16/4-way. FIXED.)
#define BLOB_BYTES 21504   // W1 8192 | W2 8192 | b1 256 | b2 256 | W3 4096 | b3 128 | pad
#define LDS_IMG 8704       // LDS image = [W2 8192 | b1 256 | b2 256] -> 27136 total w/ Hs
                           // = 53*512 exactly -> 6 blocks/CU

typedef float f4 __attribute__((ext_vector_type(4)));
typedef short s8 __attribute__((ext_vector_type(8)));          // 8 x bf16
typedef unsigned int u4 __attribute__((ext_vector_type(4)));   // same 16 B as s8

#define LOG2E  1.442695041f
#define LN2    0.6931471806f
#define SCALE2 2.885390082f   // 2*log2e: W1,b1,W2,b2 pre-scale (tanh mul folded)

__device__ __forceinline__ float rcpf(float v) { return __builtin_amdgcn_rcpf(v); }

__device__ __forceinline__ float exp2_hw(float x) {   // single v_exp_f32
#if __has_builtin(__builtin_amdgcn_exp2f)
    return __builtin_amdgcn_exp2f(x);
#else
    return exp2f(x);
#endif
}

// tanh for PRE-SCALED input (acc = 2*log2e * true_preact):
//   tanh(t) = 1 - 2/(exp2(acc)+1) — 4 instructions. Measured-minimal (r6).
__device__ __forceinline__ float fast_tanh_pre(float v) {
    float e = exp2_hw(v);
    return 1.f - 2.f * rcpf(e + 1.f);
}
// derivs chain on RAW param: 1e-3 + softplus(softplus(p)) == 1e-3 + ln(2+e^p)
__device__ __forceinline__ float deriv_chain_raw(float p) {
    return 1e-3f + LN2 * __log2f(2.f + exp2_hw(p * LOG2E));
}
// same, param pre-scaled by log2e (hot path; W3/b3 blob images carry the scale)
__device__ __forceinline__ float deriv_chain_pre(float pp) {
    return 1e-3f + LN2 * __log2f(2.f + exp2_hw(pp));
}
__device__ __forceinline__ unsigned short f2bf(float f) {   // RNE fp32->bf16
    unsigned int u = __float_as_uint(f);
    u += 0x7fffu + ((u >> 16) & 1u);
    return (unsigned short)(u >> 16);
}
#if __has_builtin(__builtin_amdgcn_cvt_pk_bf16_f32)
__device__ __forceinline__ unsigned pk2(float a, float b) {   // gfx950 packed cvt
    auto r = __builtin_amdgcn_cvt_pk_bf16_f32(a, b);
    return __builtin_bit_cast(unsigned, r);
}
#else
__device__ __forceinline__ unsigned pk2(float a, float b) {
    return (unsigned)f2bf(a) | ((unsigned)f2bf(b) << 16);
}
#endif
__device__ __forceinline__ unsigned long long pack4(float a, float b, float c, float d) {
    return (unsigned long long)pk2(a, b) | ((unsigned long long)pk2(c, d) << 32);
}

// Register-array RQS on RAW params (prep's d=0 path only; hot path inlined).
__device__ __forceinline__ void rqs_eval(const float* p, float xv, float& zout, float& ldout) {
    const bool inside = (xv >= -3.f) && (xv <= 3.f);
    const float xi = fminf(fmaxf(xv, -3.f), 3.f);

    float wa[8], ha[8];
    {   // widths = affine(softmax(6*softmax(p[0:8]))) — no max-sub (range-safe)
        float s = 0.f;
        #pragma unroll
        for (int i = 0; i < 8; i++) { wa[i] = exp2_hw(p[i] * LOG2E); s += wa[i]; }
        float inv = 6.f * rcpf(s);
        #pragma unroll
        for (int i = 0; i < 8; i++) wa[i] *= inv;
        s = 0.f;
        #pragma unroll
        for (int i = 0; i < 8; i++) { wa[i] = exp2_hw(wa[i] * LOG2E); s += wa[i]; }
        inv = 0.992f * rcpf(s);
        #pragma unroll
        for (int i = 0; i < 8; i++) wa[i] = 1e-3f + wa[i] * inv;
    }
    {
        float s = 0.f;
        #pragma unroll
        for (int i = 0; i < 8; i++) { ha[i] = exp2_hw(p[8 + i] * LOG2E); s += ha[i]; }
        float inv = 6.f * rcpf(s);
        #pragma unroll
        for (int i = 0; i < 8; i++) ha[i] *= inv;
        s = 0.f;
        #pragma unroll
        for (int i = 0; i < 8; i++) { ha[i] = exp2_hw(ha[i] * LOG2E); s += ha[i]; }
        inv = 0.992f * rcpf(s);
        #pragma unroll
        for (int i = 0; i < 8; i++) ha[i] = 1e-3f + ha[i] * inv;
    }

    float cw[9], ch[9];
    cw[0] = -3.f; ch[0] = -3.f;
    {
        float cs = 0.f, hs = 0.f;
        #pragma unroll
        for (int k = 1; k < 8; k++) {
            cs += wa[k - 1]; cw[k] = 6.f * cs - 3.f;
            hs += ha[k - 1]; ch[k] = 6.f * hs - 3.f;
        }
    }
    cw[8] = 3.f; ch[8] = 3.f;

    int cnt = 0;
    #pragma unroll
    for (int k = 0; k < 8; k++) cnt += (xi >= cw[k]) ? 1 : 0;
    cnt += (xi >= 3.000001f) ? 1 : 0;
    const int bin = min(max(cnt - 1, 0), 7);

    float in_cw = 0.f, in_w = 1.f, in_ch = 0.f, in_h = 1.f;
    float pd0 = 0.f, pd1 = 0.f;
    #pragma unroll
    for (int k = 0; k < 8; k++)
        if (k == bin) {
            in_cw = cw[k]; in_w = cw[k + 1] - cw[k];
            in_ch = ch[k]; in_h = ch[k + 1] - ch[k];
            if (k >= 1) pd0 = p[15 + k];
            if (k <= 6) pd1 = p[16 + k];
        }
    // boundary derivs are exactly 1.0
    const float dk  = (bin == 0) ? 1.f : deriv_chain_raw(pd0);
    const float dk1 = (bin == 7) ? 1.f : deriv_chain_raw(pd1);

    const float rw    = rcpf(in_w);
    const float delta = in_h * rw;
    const float th    = (xi - in_cw) * rw;
    const float omt = 1.f - th;
    const float t1  = th * omt;
    const float th2 = th * th;
    const float numer = in_h * (delta * th2 + dk * t1);
    const float denom = delta + (dk + dk1 - 2.f * delta) * t1;
    const float rd    = rcpf(denom);
    const float outv  = in_ch + numer * rd;
    const float dnum  = delta * delta * (dk1 * th2 + 2.f * delta * t1 + dk * omt * omt);
    const float ldv = LN2 * __log2f(dnum * rd * rd);

    zout  = inside ? outv : xv;
    ldout = inside ? ldv : 0.f;
}

// Prep: x -> bf16; weights -> per-layer swizzled bf16 blob with CONSTANT
// PRE-SCALES folded in: W1,b1,W2,b2 x= 2*log2e, W3,b3 x= log2e. Layout
// reshuffled so the mlp LDS image [W2|b1|b2] is one contiguous range:
//   W1 @0 | W2 @8192 | b1 @16384 | b2 @16640 | W3 @16896 | b3 @20992 | pad
__global__ __launch_bounds__(256) void prep_kernel(
    const float* __restrict__ x, const float* __restrict__ init_param,
    const float* __restrict__ W1, const float* __restrict__ W2, const float* __restrict__ W3,
    const float* __restrict__ b1, const float* __restrict__ b2, const float* __restrict__ b3,
    unsigned short* __restrict__ x_bf, unsigned char* __restrict__ blobG,
    float* __restrict__ z, float* __restrict__ ld)
{
    const int tid = threadIdx.x;
    if (blockIdx.x < 1024) {                    // x convert: 262144 quads
        size_t idx = (size_t)blockIdx.x * 256 + tid;
        f4 v = *(const f4*)&x[idx * 4];
        *(unsigned long long*)&x_bf[idx * 4] = pack4(v[0], v[1], v[2], v[3]);
        return;
    }
    if (blockIdx.x >= 1024 + LAYERS) {          // d = 0 spline + ld seed
        const int row = (blockIdx.x - 1024 - LAYERS) * 256 + tid;
        float p[23];
        #pragma unroll
        for (int j = 0; j < 23; j++) p[j] = init_param[j];
        float zv, lv;
        rqs_eval(p, x[(size_t)row * 64], zv, lv);
        z[(size_t)row * 64] = zv;
        ld[row] = lv;
        return;
    }
    const int l = blockIdx.x - 1024;
    unsigned char* gb = blobG + (size_t)l * BLOB_BYTES;
    for (int e = tid; e < 1024; e += 256) {     // W1|W2: (m, row r, block j), XOR-8 swizzle
        int m = e >> 9, r = (e >> 3) & 63, j = e & 7;
        const float* src = (m ? W2 : W1) + (size_t)l * 4096 + r * 64 + j * 8;
        unsigned long long lo = pack4(src[0] * SCALE2, src[1] * SCALE2, src[2] * SCALE2, src[3] * SCALE2);
        unsigned long long hi = pack4(src[4] * SCALE2, src[5] * SCALE2, src[6] * SCALE2, src[7] * SCALE2);
        unsigned long long* dst = (unsigned long long*)(gb + m * 8192 + r * 128 + ((j ^ (r & 7)) << 4));
        dst[0] = lo; dst[1] = hi;
    }
    if (tid < 256) {                            // W3 @16896, padded to 32 rows, x log2e
        int r = tid >> 3, j = tid & 7;
        unsigned long long lo = 0ull, hi = 0ull;
        if (r < 23) {
            const float* src = W3 + (size_t)l * 1472 + r * 64 + j * 8;
            lo = pack4(src[0] * LOG2E, src[1] * LOG2E, src[2] * LOG2E, src[3] * LOG2E);
            hi = pack4(src[4] * LOG2E, src[5] * LOG2E, src[6] * LOG2E, src[7] * LOG2E);
        }
        unsigned long long* dst = (unsigned long long*)(gb + 16896 + r * 128 + ((j ^ (r & 7)) << 4));
        dst[0] = lo; dst[1] = hi;
    }
    if (tid < 64)        *(float*)(gb + 16384 + tid * 4)         = b1[l * 64 + tid] * SCALE2;
    else if (tid < 128)  *(float*)(gb + 16640 + (tid - 64) * 4)  = b2[l * 64 + tid - 64] * SCALE2;
    else if (tid < 160)  *(float*)(gb + 20992 + (tid - 128) * 4) = (tid - 128 < 23) ? b3[l * 23 + tid - 128] * LOG2E : 0.f;
    else                 { int e = tid - 160; if (e < 96) *(float*)(gb + 21120 + e * 4) = 0.f; }
}

// One block = one layer x one 128-row tile (8064 blocks). LDS holds
// [W2 8KB DMA | b1 | b2] (8704 B) + Hs (18432 B) = 27136 = 53*512 exactly ->
// 6 blocks/CU. W1 AND W3 A-frags + b3 come straight from the L2-hot global
// blob. MEASURED-BEST r7 build (61.3 us), restored verbatim after r8.
// Lessons ledger: r2 W2-in-VGPR+(256,6) = regalloc chaos (+8us). r4 f2
// ext-vector = marshal movs (+5us). r5 1-trans poly = more instrs (+2.5us).
// r6 4-instr tanh = issue floor. r7 LDS diet -> 6 blk/CU (best). r8 barrier
// moved below GEMM1 = scheduler hoisted GEMM2/3 global loads above barrier,
// live ranges ballooned, SPILL (WRITE_SIZE 8->119 MB, +16us). Barrier
// position and load placement are LOAD-BEARING for regalloc — do not move.
__global__ __launch_bounds__(256, 6) void mlp_rqs_kernel(
    const float* __restrict__ x, const unsigned short* __restrict__ x_bf,
    const unsigned char* __restrict__ blobG,
    float* __restrict__ z, float* __restrict__ ld)
{
    const int l = blockIdx.y, keff = l + 1;
    const int b0 = blockIdx.x * BM;
    const int tid = threadIdx.x;
    const int ln = tid & 63, wv = tid >> 6;
    const int c = ln & 15, q = ln >> 4;
    const int mbase = wv * 32;
    const int c7 = c & 7;

    __shared__ __align__(16) unsigned char blob[LDS_IMG];
    __shared__ __align__(16) unsigned short Hs[BM * XS];

    unsigned short* W2s = (unsigned short*)blob;            // rows 0..63, swizzled
    const float* b1s = (const float*)(blob + 8192);
    const float* b2s = (const float*)(blob + 8448);
    float* PsF = (float*)Hs;   // Ps row r: 24 floats at word r*36 (overlay, h2 dead)

    const unsigned char* gblob = blobG + (size_t)l * BLOB_BYTES;

    // ---- async DMA: W2 (8 KB, 8 clean full-wave 1KB chunks), once per block ----
    for (int t = wv; t < 8; t += 4)
        __builtin_amdgcn_global_load_lds(
            (const __attribute__((address_space(1))) void*)(gblob + 8192 + t * 1024 + ln * 16),
            (__attribute__((address_space(3))) void*)(blob + t * 1024 + ln * 16), 16, 0, 0);
    // ---- b1|b2 (512 B contiguous @16384): 128-thread stage, same barrier ----
    if (tid < 128)
        ((float*)(blob + 8192))[tid] = *(const float*)(gblob + 16384 + tid * 4);

    const int ks1 = (keff + 31) >> 5;     // 1 or 2

    // ---- W1 A-frags -> VGPR (swizzled image, L2-hot) ----
    s8 aw1[2][4];
    #pragma unroll
    for (int mt = 0; mt < 4; mt++)
        aw1[0][mt] = *(const s8*)(gblob + (mt * 16 + c) * 128 + ((q ^ c7) << 4));
    if (ks1 == 2) {
        #pragma unroll
        for (int mt = 0; mt < 4; mt++)
            aw1[1][mt] = *(const s8*)(gblob + (mt * 16 + c) * 128 + (((4 + q) ^ c7) << 4));
    }

    // ---- X B-frags (batch rows mbase+c, mbase+16+c), tril mask in-register ----
    u4 B0u, B1u, B2u{}, B3u{};
    {
        const unsigned short* xr = x_bf + (size_t)(b0 + mbase + c) * 64 + q * 8;
        B0u = *(const u4*)xr;  B1u = *(const u4*)(xr + 1024);
        if (ks1 == 2) { B2u = *(const u4*)(xr + 32); B3u = *(const u4*)(xr + 1024 + 32); }
        const int n = keff - ((ks1 - 1) * 32 + q * 8);   // valid elems in boundary chunk
        unsigned mk[4];
        #pragma unroll
        for (int i = 0; i < 4; i++) {
            int m = n - 2 * i;
            mk[i] = (m >= 2) ? 0xFFFFFFFFu : ((m == 1) ? 0xFFFFu : 0u);
        }
        if (ks1 == 2) {
            #pragma unroll
            for (int i = 0; i < 4; i++) { B2u[i] &= mk[i]; B3u[i] &= mk[i]; }
        } else {
            #pragma unroll
            for (int i = 0; i < 4; i++) { B0u[i] &= mk[i]; B1u[i] &= mk[i]; }
        }
    }
    const float xv = x[(size_t)(b0 + (tid & 127)) * 64 + keff];   // RQS input (f32 exact)

    __syncthreads();   // LDS image resident (DMA vmcnt + ds_write lgkm drained)

    // ---- GEMM1: H1 = tanh(W1 X^T + b1), K truncated by tril ----
    {
        f4 acc[4][2];
        #pragma unroll
        for (int mt = 0; mt < 4; mt++) {
            f4 bv = *(const f4*)&b1s[mt * 16 + q * 4];
            acc[mt][0] = bv; acc[mt][1] = bv;
        }
        {
            s8 bx0 = __builtin_bit_cast(s8, B0u), bx1 = __builtin_bit_cast(s8, B1u);
            #pragma unroll
            for (int mt = 0; mt < 4; mt++) {
                acc[mt][0] = __builtin_amdgcn_mfma_f32_16x16x32_bf16(aw1[0][mt], bx0, acc[mt][0], 0, 0, 0);
                acc[mt][1] = __builtin_amdgcn_mfma_f32_16x16x32_bf16(aw1[0][mt], bx1, acc[mt][1], 0, 0, 0);
            }
        }
        if (ks1 == 2) {
            s8 bx0 = __builtin_bit_cast(s8, B2u), bx1 = __builtin_bit_cast(s8, B3u);
            #pragma unroll
            for (int mt = 0; mt < 4; mt++) {
                acc[mt][0] = __builtin_amdgcn_mfma_f32_16x16x32_bf16(aw1[1][mt], bx0, acc[mt][0], 0, 0, 0);
                acc[mt][1] = __builtin_amdgcn_mfma_f32_16x16x32_bf16(aw1[1][mt], bx1, acc[mt][1], 0, 0, 0);
            }
        }
        #pragma unroll
        for (int mt = 0; mt < 4; mt++)
            #pragma unroll
            for (int nt = 0; nt < 2; nt++) {
                f4 a = acc[mt][nt];
                unsigned long long w = (unsigned long long)pk2(fast_tanh_pre(a[0]), fast_tanh_pre(a[1]))
                    | ((unsigned long long)pk2(fast_tanh_pre(a[2]), fast_tanh_pre(a[3])) << 32);
                *(unsigned long long*)&Hs[(mbase + nt * 16 + c) * XS + mt * 16 + q * 4] = w;
            }
    }

    // ---- GEMM2: H2 = tanh(W2 H1^T + b2), wave-own rows, no barrier ----
    {
        f4 acc[4][2];
        #pragma unroll
        for (int mt = 0; mt < 4; mt++) {
            f4 bv = *(const f4*)&b2s[mt * 16 + q * 4];
            acc[mt][0] = bv; acc[mt][1] = bv;
        }
        #pragma unroll
        for (int ks = 0; ks < 2; ks++) {
            s8 bh0 = *(const s8*)&Hs[(mbase + c) * XS + ks * 32 + q * 8];
            s8 bh1 = *(const s8*)&Hs[(mbase + 16 + c) * XS + ks * 32 + q * 8];
            const int sb = ((ks * 4 + q) ^ c7) * 8;
            #pragma unroll
            for (int mt = 0; mt < 4; mt++) {
                s8 aw = *(const s8*)&W2s[(mt * 16 + c) * 64 + sb];
                acc[mt][0] = __builtin_amdgcn_mfma_f32_16x16x32_bf16(aw, bh0, acc[mt][0], 0, 0, 0);
                acc[mt][1] = __builtin_amdgcn_mfma_f32_16x16x32_bf16(aw, bh1, acc[mt][1], 0, 0, 0);
            }
        }
        #pragma unroll
        for (int mt = 0; mt < 4; mt++)
            #pragma unroll
            for (int nt = 0; nt < 2; nt++) {
                f4 a = acc[mt][nt];
                unsigned long long w = (unsigned long long)pk2(fast_tanh_pre(a[0]), fast_tanh_pre(a[1]))
                    | ((unsigned long long)pk2(fast_tanh_pre(a[2]), fast_tanh_pre(a[3])) << 32);
                *(unsigned long long*)&Hs[(mbase + nt * 16 + c) * XS + mt * 16 + q * 4] = w;
            }
    }

    // ---- GEMM3: OUT = W3 H2^T + b3 (23 outs padded 32, along m) ----
    // W3 frags (16 VGPR) + b3 straight from L2-hot blob — aw1 dead by now.
    {
        f4 acc3[2][2];
        #pragma unroll
        for (int mt = 0; mt < 2; mt++) {
            f4 bv = *(const f4*)(gblob + 20992 + (mt * 16 + q * 4) * 4);
            acc3[mt][0] = bv; acc3[mt][1] = bv;
        }
        s8 aw3[2][2];
        #pragma unroll
        for (int ks = 0; ks < 2; ks++)
            #pragma unroll
            for (int mt = 0; mt < 2; mt++)
                aw3[ks][mt] = *(const s8*)(gblob + 16896 + (mt * 16 + c) * 128 + (((ks * 4 + q) ^ c7) << 4));
        #pragma unroll
        for (int ks = 0; ks < 2; ks++) {
            s8 bh0 = *(const s8*)&Hs[(mbase + c) * XS + ks * 32 + q * 8];
            s8 bh1 = *(const s8*)&Hs[(mbase + 16 + c) * XS + ks * 32 + q * 8];
            #pragma unroll
            for (int mt = 0; mt < 2; mt++) {
                acc3[mt][0] = __builtin_amdgcn_mfma_f32_16x16x32_bf16(aw3[ks][mt], bh0, acc3[mt][0], 0, 0, 0);
                acc3[mt][1] = __builtin_amdgcn_mfma_f32_16x16x32_bf16(aw3[ks][mt], bh1, acc3[mt][1], 0, 0, 0);
            }
        }
        // Ps overlay on wave-own Hs rows (h2 dead): b128 writes
        #pragma unroll
        for (int mt = 0; mt < 2; mt++)
            #pragma unroll
            for (int nt = 0; nt < 2; nt++)
                *(f4*)&PsF[(mbase + nt * 16 + c) * 36 + mt * 16 + q * 4] = acc3[mt][nt];
    }
    __syncthreads();   // Ps complete across waves

    // ---- fused RQS: one thread per row (params pre-scaled by log2e) ----
    if (tid < BM) {
        const float* prow = &PsF[tid * 36];
        f4 pv0 = *(const f4*)(prow + 0);
        f4 pv1 = *(const f4*)(prow + 4);
        f4 pv2 = *(const f4*)(prow + 8);
        f4 pv3 = *(const f4*)(prow + 12);

        const bool inside = (xv >= -3.f) && (xv <= 3.f);
        const float xi = fminf(fmaxf(xv, -3.f), 3.f);

        float e[8];
        // ---- widths: double softmax, 6-scaled ----
        float s = 0.f;
        #pragma unroll
        for (int i = 0; i < 4; i++) { e[i]     = exp2_hw(pv0[i]); s += e[i]; }
        #pragma unroll
        for (int i = 0; i < 4; i++) { e[4 + i] = exp2_hw(pv1[i]); s += e[4 + i]; }
        float inv2 = (6.f * LOG2E) * rcpf(s);            // exp(6*e/s) = exp2(e*inv2)
        float s2 = 0.f;
        #pragma unroll
        for (int i = 0; i < 8; i++) { e[i] = exp2_hw(e[i] * inv2); s2 += e[i]; }
        float inv3 = (6.f * 0.992f) * rcpf(s2);          // width_k = 6e-3 + e*inv3 (sum=6)

        float w6k  = 6e-3f + e[0] * inv3;                 // w6[0]
        float cs   = -3.f + w6k;                          // cw[1]
        float in_cw = -3.f, in_w = w6k;
        int bin = 0;
        #pragma unroll
        for (int k = 1; k < 8; k++) {
            w6k = 6e-3f + e[k] * inv3;
            const bool ge = (xi >= cs);                   // xi >= cw[k]
            in_cw = ge ? cs  : in_cw;
            in_w  = ge ? w6k : in_w;
            bin   = ge ? k   : bin;
            cs += w6k;                                    // -> cw[k+1]
        }

        // ---- heights: same chain, select by bin ----
        s = 0.f;
        #pragma unroll
        for (int i = 0; i < 4; i++) { e[i]     = exp2_hw(pv2[i]); s += e[i]; }
        #pragma unroll
        for (int i = 0; i < 4; i++) { e[4 + i] = exp2_hw(pv3[i]); s += e[4 + i]; }
        inv2 = (6.f * LOG2E) * rcpf(s);
        s2 = 0.f;
        #pragma unroll
        for (int i = 0; i < 8; i++) { e[i] = exp2_hw(e[i] * inv2); s2 += e[i]; }
        inv3 = (6.f * 0.992f) * rcpf(s2);

        float h6p = 6e-3f + e[0] * inv3;                  // h6[0]
        float csh = -3.f, in_ch = -3.f, in_h = h6p;
        #pragma unroll
        for (int k = 1; k < 8; k++) {
            csh += h6p;                                   // ch[k]
            h6p = 6e-3f + e[k] * inv3;                    // h6[k]
            const bool sel = (bin >= k);
            in_ch = sel ? csh : in_ch;
            in_h  = sel ? h6p : in_h;
        }

        // ---- derivatives: indexed LDS reads (in-row garbage at edges, masked) ----
        const float pd0 = prow[15 + bin];
        const float pd1 = prow[16 + bin];
        const float dk  = (bin == 0) ? 1.f : deriv_chain_pre(pd0);
        const float dk1 = (bin == 7) ? 1.f : deriv_chain_pre(pd1);

        const float rw    = rcpf(in_w);
        const float delta = in_h * rw;
        const float th    = (xi - in_cw) * rw;
        const float omt = 1.f - th;
        const float t1  = th * omt;
        const float th2 = th * th;
        const float numer = in_h * (delta * th2 + dk * t1);
        const float denom = delta + (dk + dk1 - 2.f * delta) * t1;
        const float rd    = rcpf(denom);
        const float outv  = in_ch + numer * rd;
        const float dnum  = delta * delta * (dk1 * th2 + 2.f * delta * t1 + dk * omt * omt);
        const float ldv = LN2 * __log2f(dnum * rd * rd);

        z[(size_t)(b0 + tid) * 64 + keff] = inside ? outv : xv;
        unsafeAtomicAdd(ld + b0 + tid, inside ? ldv : 0.f);
    }
}

extern "C" void kernel_launch(void* const* d_in, const int* in_sizes, int n_in,
                              void* d_out, int out_size, void* d_ws, size_t ws_size,
                              hipStream_t stream)
{
    const float* x  = (const float*)d_in[0];
    const float* ip = (const float*)d_in[1];
    const float* W1 = (const float*)d_in[2];
    const float* b1 = (const float*)d_in[3];
    const float* W2 = (const float*)d_in[4];
    const float* b2 = (const float*)d_in[5];
    const float* W3 = (const float*)d_in[6];
    const float* b3 = (const float*)d_in[7];

    float* z  = (float*)d_out;                  // [B][64]
    float* ld = z + (size_t)BATCH * 64;         // [B]

    unsigned short* x_bf = (unsigned short*)d_ws;                         // [B][64] bf16
    unsigned char*  blobG = (unsigned char*)(x_bf + (size_t)BATCH * 64);  // 63 * 21504 B

    // grid: 1024 x-convert | 63 blob | 64 d0-spline blocks
    prep_kernel<<<1024 + LAYERS + 64, 256, 0, stream>>>(
        x, ip, W1, W2, W3, b1, b2, b3, x_bf, blobG, z, ld);
    mlp_rqs_kernel<<<dim3(BATCH / BM, LAYERS), 256, 0, stream>>>(
        x, x_bf, blobG, z, ld);
}